// Round 1
// baseline (379.031 us; speedup 1.0000x reference)
//
#include <hip/hip_runtime.h>
#include <hip/hip_fp16.h>

// Problem geometry: inputs (B=2, D=64, H=64, W=64, C=32) fp32, C innermost.
// Pass1: Sobel (VALID) -> mag = sqrt(gx^2+gy^2+gz^2) at 62^3 per (b,c)
// Pass2: Sobel on mag -> out = sqrt(gx^2+gy^2) + gz^2 at 60^3
// Result: mean(|out_pred - out_hr|) over 2*32*60^3 = 13,824,000 elems.
// Signs of gradients never matter (everything squared) -> conv-flip immaterial.

constexpr int BDIM = 256;
constexpr size_t IN_B = 8388608;   // 64*64*64*32 elements per batch
constexpr int IN_D = 131072;       // 64*64*32
constexpr int IN_H = 2048;         // 64*32
constexpr int M = 62;              // mag spatial dim
constexpr int F = 60;              // final spatial dim
constexpr int C = 32;
constexpr int MROW = M * C;                      // 1984 elems per (z,y) mag row
constexpr size_t MAGSZ = (size_t)M * M * MROW;   // 7,626,496 halves per buffer

// ---------------- Pass 1: input -> fp16 magnitude volume ----------------
__global__ __launch_bounds__(BDIM) void sobel_mag_kernel(
    const float* __restrict__ pred, const float* __restrict__ hr,
    __half* __restrict__ magP, __half* __restrict__ magH, int b)
{
    constexpr float S3[3] = {1.f, 2.f, 1.f};
    constexpr float D3[3] = {-1.f, 0.f, 1.f};
    const int z = blockIdx.x;   // [0,62)
    const int y = blockIdx.y;   // [0,62)
    const float* __restrict__ in  = blockIdx.z ? hr   : pred;
    __half*      __restrict__ mag = blockIdx.z ? magH : magP;

    const float* base = in + (size_t)b * IN_B + (size_t)z * IN_D + (size_t)y * IN_H;
    __half* mrow = mag + ((size_t)z * M + y) * MROW;

    for (int idx = threadIdx.x; idx < MROW; idx += BDIM) {
        // idx = x*32 + c ; input (w,c) is contiguous so base+idx is (z,y,x,c)
        const float* p0 = base + idx;
        float gx = 0.f, gy = 0.f, gz = 0.f;
#pragma unroll
        for (int i = 0; i < 3; ++i) {
#pragma unroll
            for (int j = 0; j < 3; ++j) {
                const float* p = p0 + i * IN_D + j * IN_H;
                float v0 = p[0], v1 = p[32], v2 = p[64];
                float sx = v0 + 2.f * v1 + v2;   // smooth along W
                float dx = v2 - v0;              // derivative along W
                gx += (D3[i] * S3[j]) * sx;      // d_z s_y s_x
                gy += (S3[i] * D3[j]) * sx;      // s_z d_y s_x
                gz += (S3[i] * S3[j]) * dx;      // s_z s_y d_x
            }
        }
        mrow[idx] = __float2half(sqrtf(gx * gx + gy * gy + gz * gz));
    }
}

// ------- Pass 2: mag -> final, diff pred vs hr, per-block partial sum -------
__global__ __launch_bounds__(BDIM) void sobel2_diff_kernel(
    const __half* __restrict__ magP, const __half* __restrict__ magH,
    float* __restrict__ partial, int b)
{
    constexpr float S3[3] = {1.f, 2.f, 1.f};
    constexpr float D3[3] = {-1.f, 0.f, 1.f};
    const int z = blockIdx.x;   // [0,60)
    const int y = blockIdx.y;   // [0,60)

    float acc = 0.f;
    for (int idx = threadIdx.x; idx < F * C; idx += BDIM) {
        // idx = x*32 + c, x in [0,60)
        float gxP = 0.f, gyP = 0.f, gzP = 0.f;
        float gxH = 0.f, gyH = 0.f, gzH = 0.f;
#pragma unroll
        for (int i = 0; i < 3; ++i) {
#pragma unroll
            for (int j = 0; j < 3; ++j) {
                size_t off = ((size_t)(z + i) * M + (y + j)) * MROW + idx;
                float p0 = __half2float(magP[off]);
                float p1 = __half2float(magP[off + 32]);
                float p2 = __half2float(magP[off + 64]);
                float h0 = __half2float(magH[off]);
                float h1 = __half2float(magH[off + 32]);
                float h2 = __half2float(magH[off + 64]);
                float sxP = p0 + 2.f * p1 + p2, dxP = p2 - p0;
                float sxH = h0 + 2.f * h1 + h2, dxH = h2 - h0;
                gxP += (D3[i] * S3[j]) * sxP;
                gyP += (S3[i] * D3[j]) * sxP;
                gzP += (S3[i] * S3[j]) * dxP;
                gxH += (D3[i] * S3[j]) * sxH;
                gyH += (S3[i] * D3[j]) * sxH;
                gzH += (S3[i] * S3[j]) * dxH;
            }
        }
        float outP = sqrtf(gxP * gxP + gyP * gyP) + gzP * gzP;
        float outH = sqrtf(gxH * gxH + gyH * gyH) + gzH * gzH;
        acc += fabsf(outP - outH);
    }

    // block reduction: wave64 shuffle, then across the 4 waves via LDS
    for (int o = 32; o > 0; o >>= 1) acc += __shfl_down(acc, o, 64);
    __shared__ float sred[BDIM / 64];
    const int lane = threadIdx.x & 63, wv = threadIdx.x >> 6;
    if (lane == 0) sred[wv] = acc;
    __syncthreads();
    if (threadIdx.x == 0) {
        float t = 0.f;
#pragma unroll
        for (int i = 0; i < BDIM / 64; ++i) t += sred[i];
        partial[(size_t)b * (F * F) + (size_t)z * F + y] = t;
    }
}

// ---------------- Finalize: sum 7200 partials in double, write mean ----------------
__global__ __launch_bounds__(BDIM) void finalize_kernel(
    const float* __restrict__ partial, float* __restrict__ out)
{
    double a = 0.0;
    for (int i = threadIdx.x; i < 2 * F * F; i += BDIM) a += (double)partial[i];
    for (int o = 32; o > 0; o >>= 1) a += __shfl_down(a, o, 64);
    __shared__ double sd[BDIM / 64];
    const int lane = threadIdx.x & 63, wv = threadIdx.x >> 6;
    if (lane == 0) sd[wv] = a;
    __syncthreads();
    if (threadIdx.x == 0) {
        double t = 0.0;
#pragma unroll
        for (int i = 0; i < BDIM / 64; ++i) t += sd[i];
        out[0] = (float)(t / 13824000.0);
    }
}

extern "C" void kernel_launch(void* const* d_in, const int* in_sizes, int n_in,
                              void* d_out, int out_size, void* d_ws, size_t ws_size,
                              hipStream_t stream)
{
    const float* pred = (const float*)d_in[0];
    const float* hr   = (const float*)d_in[1];

    // ws layout: [0, 28.8KB): 7200 float partials (fully overwritten each call)
    //            [64KB, ...): magP (fp16, 7.6M), magH (fp16, 7.6M)  ~29.2 MiB total
    float* partial = (float*)d_ws;
    __half* magP = (__half*)((char*)d_ws + 65536);
    __half* magH = magP + MAGSZ;

    for (int b = 0; b < 2; ++b) {
        sobel_mag_kernel<<<dim3(M, M, 2), BDIM, 0, stream>>>(pred, hr, magP, magH, b);
        sobel2_diff_kernel<<<dim3(F, F), BDIM, 0, stream>>>(magP, magH, partial, b);
    }
    finalize_kernel<<<1, BDIM, 0, stream>>>(partial, (float*)d_out);
}